// Round 2
// baseline (496.163 us; speedup 1.0000x reference)
//
#include <hip/hip_runtime.h>
#include <hip/hip_bf16.h>

typedef __bf16 bf16x8 __attribute__((ext_vector_type(8)));
typedef float f32x4 __attribute__((ext_vector_type(4)));

#define NHEADS 12
#define TT 40
#define ST 1024
#define NTOK 1064
#define CDIM 768
#define HD 64

union U4 {
    uint4 u;
    __hip_bfloat16 h[8];
    bf16x8 v;
};

// Load 8 consecutive elements of one row (k0..k0+7), converting fp32->bf16 if needed.
template <bool F32>
__device__ inline U4 load_row8(const void* __restrict__ src, long long rowbase,
                               int k0, int K, bool valid)
{
    U4 r;
    if (!valid) { r.u = make_uint4(0u, 0u, 0u, 0u); return r; }
    if constexpr (F32) {
        const float* p = (const float*)src + rowbase + k0;
        if (k0 + 8 <= K) {
            float4 a = ((const float4*)p)[0];
            float4 b = ((const float4*)p)[1];
            r.h[0] = __float2bfloat16(a.x); r.h[1] = __float2bfloat16(a.y);
            r.h[2] = __float2bfloat16(a.z); r.h[3] = __float2bfloat16(a.w);
            r.h[4] = __float2bfloat16(b.x); r.h[5] = __float2bfloat16(b.y);
            r.h[6] = __float2bfloat16(b.z); r.h[7] = __float2bfloat16(b.w);
        } else {
            for (int i = 0; i < 8; ++i)
                r.h[i] = (k0 + i < K) ? __float2bfloat16(p[i]) : __float2bfloat16(0.0f);
        }
    } else {
        const __hip_bfloat16* p = (const __hip_bfloat16*)src + rowbase + k0;
        if (k0 + 8 <= K) {
            r.u = *(const uint4*)p;
        } else {
            for (int i = 0; i < 8; ++i)
                r.h[i] = (k0 + i < K) ? p[i] : __float2bfloat16(0.0f);
        }
    }
    return r;
}

// Batched NT GEMM: out[g,i,j] = sum_k A[g][i*lda+k] * B[g][j*ldb+k]
// Tile 64x64, 256 threads = 4 waves, each wave owns a 16-row strip.
// MODE 0: QKV scatter -> Q,K,VT   MODE 1: scores   MODE 2: PV -> attn_out
// MODE 3: proj + bias -> float out
template <int MODE, bool AF32, bool BF32>
__global__ __launch_bounds__(256) void gemm_nt(
    const void* __restrict__ A, int lda, long long Astride,
    const void* __restrict__ B, int ldb, long long Bstride,
    int K, int Ntot,
    __hip_bfloat16* __restrict__ out0,
    __hip_bfloat16* __restrict__ out1,
    __hip_bfloat16* __restrict__ out2,
    float* __restrict__ outf,
    const float* __restrict__ biasf,
    int ghbase)
{
    __shared__ uint4 lds[640];              // A: [0,320) u4, B: [320,640) u4 (row stride 40 bf16)
    __hip_bfloat16* ldsh = (__hip_bfloat16*)lds;

    const int tid = threadIdx.x;
    const int g = blockIdx.z;
    const char* Ag = (const char*)A + (long long)g * Astride * (AF32 ? 4 : 2);
    const char* Bg = (const char*)B + (long long)g * Bstride * (BF32 ? 4 : 2);
    const int m0 = blockIdx.y * 64;
    const int n0 = blockIdx.x * 64;

    const int srow = tid >> 2;   // 0..63 staging row
    const int sseg = tid & 3;    // 0..3 k-segment of 8
    const int w = tid >> 6;      // wave id
    const int l = tid & 63;
    const int l15 = l & 15;
    const int lq = l >> 4;

    f32x4 acc[4] = {};

    const int ksteps = (K + 31) / 32;
    for (int ks = 0; ks < ksteps; ++ks) {
        const int k0 = ks * 32 + sseg * 8;
        if (ks) __syncthreads();
        U4 va = load_row8<AF32>(Ag, (long long)(m0 + srow) * lda, k0, K, true);
        const int brow = n0 + srow;
        U4 vb = load_row8<BF32>(Bg, (long long)brow * ldb, k0, K, brow < Ntot);
        lds[srow * 5 + sseg] = va.u;
        lds[320 + srow * 5 + sseg] = vb.u;
        __syncthreads();

        bf16x8 af = *(const bf16x8*)(ldsh + (w * 16 + l15) * 40 + lq * 8);
#pragma unroll
        for (int t = 0; t < 4; ++t) {
            bf16x8 bf = *(const bf16x8*)(ldsh + 2560 + (t * 16 + l15) * 40 + lq * 8);
            acc[t] = __builtin_amdgcn_mfma_f32_16x16x32_bf16(af, bf, acc[t], 0, 0, 0);
        }
    }

#pragma unroll
    for (int t = 0; t < 4; ++t) {
#pragma unroll
        for (int i = 0; i < 4; ++i) {
            const int row = m0 + w * 16 + lq * 4 + i;   // C/D: row=(lane>>4)*4+reg
            const int col = n0 + t * 16 + l15;          //      col=lane&15
            const float v = acc[t][i];
            if (MODE == 0) {
                const int b = row / NTOK;
                const int n = row - b * NTOK;
                const int tq = col / CDIM;
                const int rem = col - tq * CDIM;
                const int h = rem >> 6;
                const int e = rem & 63;
                const long long gh = (long long)b * NHEADS + h;
                const __hip_bfloat16 hv = __float2bfloat16(v);
                if (tq == 0)      out0[(gh * NTOK + n) * HD + e] = hv;   // Q [b,h,n,e]
                else if (tq == 1) out1[(gh * NTOK + n) * HD + e] = hv;   // K [b,h,n,e]
                else              out2[(gh * HD + e) * NTOK + n] = hv;   // VT [b,h,e,n]
            } else if (MODE == 1) {
                if (col < Ntot)
                    out0[((long long)g * ST + row) * NTOK + col] = __float2bfloat16(v);
            } else if (MODE == 2) {
                const int gh = ghbase + g;
                const int b = gh / NHEADS;
                const int h = gh - b * NHEADS;
                out0[((long long)b * NTOK + TT + row) * CDIM + h * HD + col] = __float2bfloat16(v);
            } else {
                outf[(long long)row * CDIM + col] = v + biasf[col];
            }
        }
    }
}

// Row softmax in place over bf16 scores, row length NTOK, scale 1/8 applied here.
__global__ __launch_bounds__(256) void softmax_rows(__hip_bfloat16* __restrict__ s)
{
    const int row = blockIdx.x * 4 + (threadIdx.x >> 6);
    const int lane = threadIdx.x & 63;
    __hip_bfloat16* p = s + (long long)row * NTOK;
    float v[17];
    float m = -1e30f;
#pragma unroll
    for (int it = 0; it < 17; ++it) {
        const int j = it * 64 + lane;
        const float x = (j < NTOK) ? __bfloat162float(p[j]) * 0.125f : -1e30f;
        v[it] = x;
        m = fmaxf(m, x);
    }
    for (int off = 32; off > 0; off >>= 1) m = fmaxf(m, __shfl_xor(m, off));
    float ssum = 0.0f;
#pragma unroll
    for (int it = 0; it < 17; ++it) {
        const int j = it * 64 + lane;
        const float e = (j < NTOK) ? __expf(v[it] - m) : 0.0f;
        v[it] = e;
        ssum += e;
    }
    for (int off = 32; off > 0; off >>= 1) ssum += __shfl_xor(ssum, off);
    const float inv = 1.0f / ssum;
#pragma unroll
    for (int it = 0; it < 17; ++it) {
        const int j = it * 64 + lane;
        if (j < NTOK) p[j] = __float2bfloat16(v[it] * inv);
    }
}

// Text attention: 96 blocks, one (b,h) each. Text queries attend over 40 text keys only.
__global__ __launch_bounds__(256) void text_attn(
    const __hip_bfloat16* __restrict__ Q,
    const __hip_bfloat16* __restrict__ Kt,
    const __hip_bfloat16* __restrict__ VT,
    __hip_bfloat16* __restrict__ AO)
{
    const int gh = blockIdx.x;
    const int b = gh / NHEADS;
    const int h = gh - b * NHEADS;
    __shared__ float smem[3 * 40 * 65];
    float* Qs = smem;
    float* Ks = smem + 40 * 65;
    float* Vs = smem + 2 * 40 * 65;
    const __hip_bfloat16* Qg = Q + (long long)gh * NTOK * HD;
    const __hip_bfloat16* Kg = Kt + (long long)gh * NTOK * HD;
    const __hip_bfloat16* Vg = VT + (long long)gh * HD * NTOK;
    for (int idx = threadIdx.x; idx < 40 * 64; idx += 256) {
        const int n = idx >> 6;
        const int e = idx & 63;
        Qs[n * 65 + e] = __bfloat162float(Qg[n * HD + e]);
        Ks[n * 65 + e] = __bfloat162float(Kg[n * HD + e]);
        Vs[n * 65 + e] = __bfloat162float(Vg[(long long)e * NTOK + n]);
    }
    __syncthreads();
    const int w = threadIdx.x >> 6;
    const int lane = threadIdx.x & 63;
    for (int i = w; i < TT; i += 4) {
        float s = -1e30f;
        if (lane < TT) {
            float a = 0.0f;
            for (int e = 0; e < 64; ++e) a += Qs[i * 65 + e] * Ks[lane * 65 + e];
            s = a * 0.125f;
        }
        float m = s;
        for (int off = 32; off > 0; off >>= 1) m = fmaxf(m, __shfl_xor(m, off));
        float pr = (lane < TT) ? __expf(s - m) : 0.0f;
        float ssum = pr;
        for (int off = 32; off > 0; off >>= 1) ssum += __shfl_xor(ssum, off);
        pr /= ssum;
        float o = 0.0f;
        for (int j = 0; j < TT; ++j) o += __shfl(pr, j) * Vs[j * 65 + lane];
        AO[((long long)b * NTOK + i) * CDIM + h * HD + lane] = __float2bfloat16(o);
    }
}

extern "C" void kernel_launch(void* const* d_in, const int* in_sizes, int n_in,
                              void* d_out, int out_size, void* d_ws, size_t ws_size,
                              hipStream_t stream)
{
    const float* x      = (const float*)d_in[0];
    const float* qkv_w  = (const float*)d_in[1];
    const float* proj_w = (const float*)d_in[2];
    const float* proj_b = (const float*)d_in[3];
    float* out = (float*)d_out;

    const long long QKV_ELEMS = (long long)8 * NHEADS * NTOK * HD;  // 6,537,216
    __hip_bfloat16* Q  = (__hip_bfloat16*)d_ws;
    __hip_bfloat16* Kt = Q + QKV_ELEMS;
    __hip_bfloat16* VT = Kt + QKV_ELEMS;
    __hip_bfloat16* AO = VT + QKV_ELEMS;        // [B,N,C] bf16
    __hip_bfloat16* SC = AO + QKV_ELEMS;        // score chunk [G][1024][1064] bf16

    // pick largest head-group chunk G that fits ws (constant per session -> graph-safe)
    const size_t fixed_bytes = (size_t)(4 * QKV_ELEMS) * 2;
    int G = 3;
    const int cand[3] = {24, 12, 6};
    for (int ci = 0; ci < 3; ++ci) {
        const size_t need = fixed_bytes + (size_t)cand[ci] * ST * NTOK * 2;
        if (need <= ws_size) { G = cand[ci]; break; }
    }

    // 1. QKV GEMM: M=8512, N=2304, K=768  (fp32 in -> bf16 Q/K/VT)
    gemm_nt<0, true, true><<<dim3(36, 133, 1), 256, 0, stream>>>(
        x, CDIM, 0LL, qkv_w, CDIM, 0LL, CDIM, 3 * CDIM,
        Q, Kt, VT, nullptr, nullptr, 0);

    // 2. text attention (rows 0..39 of AO per batch)
    text_attn<<<96, 256, 0, stream>>>(Q, Kt, VT, AO);

    // 3. image attention in chunks of G (b,h) pairs
    for (int ghbase = 0; ghbase < 96; ghbase += G) {
        gemm_nt<1, false, false><<<dim3(17, 16, G), 256, 0, stream>>>(
            Q + ((long long)ghbase * NTOK + TT) * HD, HD, (long long)NTOK * HD,
            Kt + (long long)ghbase * NTOK * HD, HD, (long long)NTOK * HD,
            HD, NTOK, SC, nullptr, nullptr, nullptr, nullptr, ghbase);
        softmax_rows<<<G * 256, 256, 0, stream>>>(SC);
        gemm_nt<2, false, false><<<dim3(1, 16, G), 256, 0, stream>>>(
            SC, NTOK, (long long)ST * NTOK,
            VT + (long long)ghbase * HD * NTOK, NTOK, (long long)HD * NTOK,
            NTOK, HD, AO, nullptr, nullptr, nullptr, nullptr, ghbase);
    }

    // 4. proj GEMM + bias: M=8512, N=768, K=768  (bf16 AO x fp32 W -> fp32 out)
    gemm_nt<3, false, true><<<dim3(12, 133, 1), 256, 0, stream>>>(
        AO, CDIM, 0LL, proj_w, CDIM, 0LL, CDIM, CDIM,
        nullptr, nullptr, nullptr, out, proj_b, 0);
}

// Round 3
// 292.316 us; speedup vs baseline: 1.6973x; 1.6973x over previous
//
#include <hip/hip_runtime.h>
#include <hip/hip_bf16.h>

typedef __bf16 bf16x8 __attribute__((ext_vector_type(8)));
typedef float f32x4 __attribute__((ext_vector_type(4)));

#define NHEADS 12
#define TT 40
#define ST 1024
#define NTOK 1064
#define CDIM 768
#define HD 64

union U4 {
    uint4 u;
    __hip_bfloat16 h[8];
    bf16x8 v;
};

template <bool F32>
__device__ inline U4 load_row8(const void* __restrict__ src, long long rowbase,
                               int k0, int K, bool valid)
{
    U4 r;
    if (!valid) { r.u = make_uint4(0u, 0u, 0u, 0u); return r; }
    if constexpr (F32) {
        const float* p = (const float*)src + rowbase + k0;
        if (k0 + 8 <= K) {
            float4 a = ((const float4*)p)[0];
            float4 b = ((const float4*)p)[1];
            r.h[0] = __float2bfloat16(a.x); r.h[1] = __float2bfloat16(a.y);
            r.h[2] = __float2bfloat16(a.z); r.h[3] = __float2bfloat16(a.w);
            r.h[4] = __float2bfloat16(b.x); r.h[5] = __float2bfloat16(b.y);
            r.h[6] = __float2bfloat16(b.z); r.h[7] = __float2bfloat16(b.w);
        } else {
            for (int i = 0; i < 8; ++i)
                r.h[i] = (k0 + i < K) ? __float2bfloat16(p[i]) : __float2bfloat16(0.0f);
        }
    } else {
        const __hip_bfloat16* p = (const __hip_bfloat16*)src + rowbase + k0;
        if (k0 + 8 <= K) {
            r.u = *(const uint4*)p;
        } else {
            for (int i = 0; i < 8; ++i)
                r.h[i] = (k0 + i < K) ? p[i] : __float2bfloat16(0.0f);
        }
    }
    return r;
}

// fp32 -> bf16 elementwise convert, 8 elems/thread (n8 = n/8, n % 8 == 0)
__global__ __launch_bounds__(256) void f2b(const float* __restrict__ in,
                                           __hip_bfloat16* __restrict__ out, int n8)
{
    const int i = blockIdx.x * 256 + threadIdx.x;
    if (i >= n8) return;
    float4 a = ((const float4*)in)[2 * i];
    float4 b = ((const float4*)in)[2 * i + 1];
    U4 r;
    r.h[0] = __float2bfloat16(a.x); r.h[1] = __float2bfloat16(a.y);
    r.h[2] = __float2bfloat16(a.z); r.h[3] = __float2bfloat16(a.w);
    r.h[4] = __float2bfloat16(b.x); r.h[5] = __float2bfloat16(b.y);
    r.h[6] = __float2bfloat16(b.z); r.h[7] = __float2bfloat16(b.w);
    ((uint4*)out)[i] = r.u;
}

// Batched NT GEMM (64x64 tile, 4 waves). MODE 0: QKV scatter; MODE 3: proj+bias->fp32
template <int MODE, bool AF32, bool BF32>
__global__ __launch_bounds__(256) void gemm_nt(
    const void* __restrict__ A, int lda, long long Astride,
    const void* __restrict__ B, int ldb, long long Bstride,
    int K, int Ntot,
    __hip_bfloat16* __restrict__ out0,
    __hip_bfloat16* __restrict__ out1,
    __hip_bfloat16* __restrict__ out2,
    float* __restrict__ outf,
    const float* __restrict__ biasf,
    int ghbase)
{
    __shared__ uint4 lds[640];
    __hip_bfloat16* ldsh = (__hip_bfloat16*)lds;

    const int tid = threadIdx.x;
    const int g = blockIdx.z;
    const char* Ag = (const char*)A + (long long)g * Astride * (AF32 ? 4 : 2);
    const char* Bg = (const char*)B + (long long)g * Bstride * (BF32 ? 4 : 2);
    const int m0 = blockIdx.y * 64;
    const int n0 = blockIdx.x * 64;

    const int srow = tid >> 2;
    const int sseg = tid & 3;
    const int w = tid >> 6;
    const int l = tid & 63;
    const int l15 = l & 15;
    const int lq = l >> 4;

    f32x4 acc[4] = {};

    const int ksteps = (K + 31) / 32;
    for (int ks = 0; ks < ksteps; ++ks) {
        const int k0 = ks * 32 + sseg * 8;
        if (ks) __syncthreads();
        U4 va = load_row8<AF32>(Ag, (long long)(m0 + srow) * lda, k0, K, true);
        const int brow = n0 + srow;
        U4 vb = load_row8<BF32>(Bg, (long long)brow * ldb, k0, K, brow < Ntot);
        lds[srow * 5 + sseg] = va.u;
        lds[320 + srow * 5 + sseg] = vb.u;
        __syncthreads();

        bf16x8 af = *(const bf16x8*)(ldsh + (w * 16 + l15) * 40 + lq * 8);
#pragma unroll
        for (int t = 0; t < 4; ++t) {
            bf16x8 bf = *(const bf16x8*)(ldsh + 2560 + (t * 16 + l15) * 40 + lq * 8);
            acc[t] = __builtin_amdgcn_mfma_f32_16x16x32_bf16(af, bf, acc[t], 0, 0, 0);
        }
    }

#pragma unroll
    for (int t = 0; t < 4; ++t) {
#pragma unroll
        for (int i = 0; i < 4; ++i) {
            const int row = m0 + w * 16 + lq * 4 + i;
            const int col = n0 + t * 16 + l15;
            const float v = acc[t][i];
            if (MODE == 0) {
                const int b = row / NTOK;
                const int n = row - b * NTOK;
                const int tq = col / CDIM;
                const int rem = col - tq * CDIM;
                const int h = rem >> 6;
                const int e = rem & 63;
                const long long gh = (long long)b * NHEADS + h;
                const __hip_bfloat16 hv = __float2bfloat16(v);
                if (tq == 0)      out0[(gh * NTOK + n) * HD + e] = hv;   // Q [b,h,n,e]
                else if (tq == 1) out1[(gh * NTOK + n) * HD + e] = hv;   // K [b,h,n,e]
                else              out2[(gh * HD + e) * NTOK + n] = hv;   // VT [b,h,e,n]
            } else {
                outf[(long long)row * CDIM + col] = v + biasf[col];
            }
        }
    }
}

// ---------------------------------------------------------------------------
// Flash image attention. One block = one (b,h) x 128-row Q-tile. 256 thr = 4 waves.
// Computes S^T = K·Q^T (MFMA), online softmax along lane15 axis, O^T = VT·P^T
// with P^T B-frags built from S^T C-layout via intra-wave shuffles.
// ---------------------------------------------------------------------------
__global__ __launch_bounds__(256) void flash_img(
    const __hip_bfloat16* __restrict__ Q,   // [96][1064][64]
    const __hip_bfloat16* __restrict__ Kt,  // [96][1064][64]
    const __hip_bfloat16* __restrict__ VT,  // [96][64][1064]
    __hip_bfloat16* __restrict__ AO)        // [8][1064][768]
{
    __shared__ __hip_bfloat16 smem[2 * 64 * 72];   // kbuf | vbuf ; reused as obuf[128][72]
    __hip_bfloat16* kbuf = smem;
    __hip_bfloat16* vbuf = smem + 64 * 72;

    const int gh = blockIdx.y;
    const int qt = blockIdx.x;
    const int tid = threadIdx.x;
    const int w = tid >> 6, l = tid & 63, l15 = l & 15, lq = l >> 4;

    const __hip_bfloat16* Qg = Q + ((long long)gh * NTOK + TT + qt * 128) * HD;
    const __hip_bfloat16* Kg = Kt + (long long)gh * NTOK * HD;
    const __hip_bfloat16* Vg = VT + (long long)gh * HD * NTOK;

    // Q fragments (B-operand): qf[s][kk] = Q[w*32 + s*16 + l15][kk*32 + lq*8 .. +8]
    bf16x8 qf[2][2];
#pragma unroll
    for (int s = 0; s < 2; ++s)
#pragma unroll
        for (int kk = 0; kk < 2; ++kk)
            qf[s][kk] = *(const bf16x8*)(Qg + (w * 32 + s * 16 + l15) * HD + kk * 32 + lq * 8);

    f32x4 ot[4][2] = {};                    // O^T: rows e=te*16+lq*4+i, col m = s*16+l15
    float mrow[2] = {-3e38f, -3e38f};
    float lrow[2] = {0.0f, 0.0f};

    for (int kt = 0; kt < 17; ++kt) {
        const int n0 = kt * 64;
        if (kt) __syncthreads();
        // ---- stage K-tile [key n][dim] and VT-tile [dim][key n] ----
        {
            const int r = tid >> 2, c16 = (tid & 3) * 16;
            if (kt < 16) {
                *(uint4*)(kbuf + r * 72 + c16)     = *(const uint4*)(Kg + (long long)(n0 + r) * HD + c16);
                *(uint4*)(kbuf + r * 72 + c16 + 8) = *(const uint4*)(Kg + (long long)(n0 + r) * HD + c16 + 8);
                *(uint4*)(vbuf + r * 72 + c16)     = *(const uint4*)(Vg + (long long)r * NTOK + n0 + c16);
                *(uint4*)(vbuf + r * 72 + c16 + 8) = *(const uint4*)(Vg + (long long)r * NTOK + n0 + c16 + 8);
            } else {
                const uint4 z = make_uint4(0u, 0u, 0u, 0u);
                if (n0 + r < NTOK) {
                    *(uint4*)(kbuf + r * 72 + c16)     = *(const uint4*)(Kg + (long long)(n0 + r) * HD + c16);
                    *(uint4*)(kbuf + r * 72 + c16 + 8) = *(const uint4*)(Kg + (long long)(n0 + r) * HD + c16 + 8);
                } else {
                    *(uint4*)(kbuf + r * 72 + c16) = z;
                    *(uint4*)(kbuf + r * 72 + c16 + 8) = z;
                }
                for (int j = 0; j < 16; ++j) {
                    const int cc = c16 + j;
                    vbuf[r * 72 + cc] = (n0 + cc < NTOK) ? Vg[(long long)r * NTOK + n0 + cc]
                                                         : __float2bfloat16(0.0f);
                }
            }
        }
        __syncthreads();

        // ---- S^T = K · Q^T : st[t][s], rows n = t*16+lq*4+i, col m = s*16+l15 ----
        f32x4 st[4][2] = {};
#pragma unroll
        for (int kk = 0; kk < 2; ++kk) {
            bf16x8 kf[4];
#pragma unroll
            for (int t = 0; t < 4; ++t)
                kf[t] = *(const bf16x8*)(kbuf + (t * 16 + l15) * 72 + kk * 32 + lq * 8);
#pragma unroll
            for (int t = 0; t < 4; ++t)
#pragma unroll
                for (int s = 0; s < 2; ++s)
                    st[t][s] = __builtin_amdgcn_mfma_f32_16x16x32_bf16(kf[t], qf[s][kk], st[t][s], 0, 0, 0);
        }

        // ---- online softmax along n (stats per m; m lives on l15/s axes) ----
        float alpha[2];
#pragma unroll
        for (int s = 0; s < 2; ++s) {
            float mx = -3e38f;
#pragma unroll
            for (int t = 0; t < 4; ++t)
#pragma unroll
                for (int i = 0; i < 4; ++i) {
                    const int n = n0 + t * 16 + lq * 4 + i;
                    const float sv = (n < NTOK) ? st[t][s][i] * 0.125f : -3e38f;
                    st[t][s][i] = sv;
                    mx = fmaxf(mx, sv);
                }
            mx = fmaxf(mx, __shfl_xor(mx, 16));
            mx = fmaxf(mx, __shfl_xor(mx, 32));
            const float mnew = fmaxf(mrow[s], mx);
            alpha[s] = __expf(mrow[s] - mnew);
            float rs = 0.0f;
#pragma unroll
            for (int t = 0; t < 4; ++t)
#pragma unroll
                for (int i = 0; i < 4; ++i) {
                    const float e = __expf(st[t][s][i] - mnew);
                    st[t][s][i] = e;
                    rs += e;
                }
            rs += __shfl_xor(rs, 16);
            rs += __shfl_xor(rs, 32);
            lrow[s] = lrow[s] * alpha[s] + rs;
            mrow[s] = mnew;
        }

        // rescale O^T
#pragma unroll
        for (int te = 0; te < 4; ++te)
#pragma unroll
            for (int s = 0; s < 2; ++s)
#pragma unroll
                for (int i = 0; i < 4; ++i)
                    ot[te][s][i] *= alpha[s];

        // pack P^T (st) into bf16 pairs: pk[t][s][h] = (p[2h] | p[2h+1]<<16)
        unsigned pk[4][2][2];
#pragma unroll
        for (int t = 0; t < 4; ++t)
#pragma unroll
            for (int s = 0; s < 2; ++s)
#pragma unroll
                for (int h = 0; h < 2; ++h) {
                    __hip_bfloat162 b2;
                    b2.x = __float2bfloat16(st[t][s][2 * h]);
                    b2.y = __float2bfloat16(st[t][s][2 * h + 1]);
                    pk[t][s][h] = *(unsigned*)&b2;
                }

        // ---- O^T += VT-tile · P^T ----
        const int L0 = ((l & 16) ? 32 : 0) + l15;   // src lane group, j 0..3
        const int L1 = L0 + 16;                     // j 4..7
        const bool hi = (l & 32) != 0;              // selects t = 2kk+1
#pragma unroll
        for (int kk = 0; kk < 2; ++kk) {
            bf16x8 vf[4];
#pragma unroll
            for (int te = 0; te < 4; ++te)
                vf[te] = *(const bf16x8*)(vbuf + (te * 16 + l15) * 72 + kk * 32 + lq * 8);
#pragma unroll
            for (int s = 0; s < 2; ++s) {
                const unsigned a0 = __shfl(pk[2 * kk][s][0], L0), b0 = __shfl(pk[2 * kk + 1][s][0], L0);
                const unsigned a1 = __shfl(pk[2 * kk][s][1], L0), b1 = __shfl(pk[2 * kk + 1][s][1], L0);
                const unsigned a2 = __shfl(pk[2 * kk][s][0], L1), b2 = __shfl(pk[2 * kk + 1][s][0], L1);
                const unsigned a3 = __shfl(pk[2 * kk][s][1], L1), b3 = __shfl(pk[2 * kk + 1][s][1], L1);
                union { unsigned u[4]; bf16x8 v; } pu;
                pu.u[0] = hi ? b0 : a0;
                pu.u[1] = hi ? b1 : a1;
                pu.u[2] = hi ? b2 : a2;
                pu.u[3] = hi ? b3 : a3;
#pragma unroll
                for (int te = 0; te < 4; ++te)
                    ot[te][s] = __builtin_amdgcn_mfma_f32_16x16x32_bf16(vf[te], pu.v, ot[te][s], 0, 0, 0);
            }
        }
    }

    // ---- epilogue: O = O^T / l, transpose via LDS, coalesced write ----
    __syncthreads();
    __hip_bfloat16* obuf = smem;                 // [128][72]
    const float inv[2] = {1.0f / lrow[0], 1.0f / lrow[1]};
#pragma unroll
    for (int te = 0; te < 4; ++te)
#pragma unroll
        for (int s = 0; s < 2; ++s) {
            __hip_bfloat162 x0, x1;
            x0.x = __float2bfloat16(ot[te][s][0] * inv[s]);
            x0.y = __float2bfloat16(ot[te][s][1] * inv[s]);
            x1.x = __float2bfloat16(ot[te][s][2] * inv[s]);
            x1.y = __float2bfloat16(ot[te][s][3] * inv[s]);
            uint2 u;
            u.x = *(unsigned*)&x0;
            u.y = *(unsigned*)&x1;
            *(uint2*)(obuf + (w * 32 + s * 16 + l15) * 72 + te * 16 + lq * 4) = u;
        }
    __syncthreads();
    {
        const int b = gh / NHEADS, h = gh - b * NHEADS;
        const int r = tid >> 1, c0 = (tid & 1) * 32;
        const int token = TT + qt * 128 + r;
        __hip_bfloat16* dst = AO + ((long long)b * NTOK + token) * CDIM + h * HD + c0;
#pragma unroll
        for (int i = 0; i < 4; ++i)
            *(uint4*)(dst + i * 8) = *(const uint4*)(obuf + r * 72 + c0 + i * 8);
    }
}

// Text attention: 96 blocks, one (b,h) each; 40 text queries over 40 text keys.
__global__ __launch_bounds__(256) void text_attn(
    const __hip_bfloat16* __restrict__ Q,
    const __hip_bfloat16* __restrict__ Kt,
    const __hip_bfloat16* __restrict__ VT,
    __hip_bfloat16* __restrict__ AO)
{
    const int gh = blockIdx.x;
    const int b = gh / NHEADS;
    const int h = gh - b * NHEADS;
    __shared__ float smem[3 * 40 * 65];
    float* Qs = smem;
    float* Ks = smem + 40 * 65;
    float* Vs = smem + 2 * 40 * 65;
    const __hip_bfloat16* Qg = Q + (long long)gh * NTOK * HD;
    const __hip_bfloat16* Kg = Kt + (long long)gh * NTOK * HD;
    const __hip_bfloat16* Vg = VT + (long long)gh * HD * NTOK;
    for (int idx = threadIdx.x; idx < 40 * 64; idx += 256) {
        const int n = idx >> 6;
        const int e = idx & 63;
        Qs[n * 65 + e] = __bfloat162float(Qg[n * HD + e]);
        Ks[n * 65 + e] = __bfloat162float(Kg[n * HD + e]);
        Vs[n * 65 + e] = __bfloat162float(Vg[(long long)e * NTOK + n]);
    }
    __syncthreads();
    const int w = threadIdx.x >> 6;
    const int lane = threadIdx.x & 63;
    for (int i = w; i < TT; i += 4) {
        float s = -1e30f;
        if (lane < TT) {
            float a = 0.0f;
            for (int e = 0; e < 64; ++e) a += Qs[i * 65 + e] * Ks[lane * 65 + e];
            s = a * 0.125f;
        }
        float m = s;
        for (int off = 32; off > 0; off >>= 1) m = fmaxf(m, __shfl_xor(m, off));
        float pr = (lane < TT) ? __expf(s - m) : 0.0f;
        float ssum = pr;
        for (int off = 32; off > 0; off >>= 1) ssum += __shfl_xor(ssum, off);
        pr /= ssum;
        float o = 0.0f;
        for (int j = 0; j < TT; ++j) o += __shfl(pr, j) * Vs[j * 65 + lane];
        AO[((long long)b * NTOK + i) * CDIM + h * HD + lane] = __float2bfloat16(o);
    }
}

extern "C" void kernel_launch(void* const* d_in, const int* in_sizes, int n_in,
                              void* d_out, int out_size, void* d_ws, size_t ws_size,
                              hipStream_t stream)
{
    const float* x      = (const float*)d_in[0];
    const float* qkv_w  = (const float*)d_in[1];
    const float* proj_w = (const float*)d_in[2];
    const float* proj_b = (const float*)d_in[3];
    float* out = (float*)d_out;

    const long long QKV_ELEMS = (long long)8 * NHEADS * NTOK * HD;  // 6,537,216
    __hip_bfloat16* Q  = (__hip_bfloat16*)d_ws;
    __hip_bfloat16* Kt = Q + QKV_ELEMS;
    __hip_bfloat16* VT = Kt + QKV_ELEMS;
    __hip_bfloat16* AO = VT + QKV_ELEMS;        // [8][1064][768] bf16; ALIASES xb
    __hip_bfloat16* xb = AO;                    // x bf16 [8512][768] (same size, dead after QKV)
    __hip_bfloat16* wb = AO + QKV_ELEMS;        // qkv_w bf16 [2304][768]
    __hip_bfloat16* pb = wb + (long long)3 * CDIM * CDIM;  // proj_w bf16 [768][768]

    // 0. fp32 -> bf16 converts
    f2b<<<(6537216 / 8 + 255) / 256, 256, 0, stream>>>(x, xb, 6537216 / 8);
    f2b<<<(1769472 / 8 + 255) / 256, 256, 0, stream>>>(qkv_w, wb, 1769472 / 8);
    f2b<<<(589824 / 8 + 255) / 256, 256, 0, stream>>>(proj_w, pb, 589824 / 8);

    // 1. QKV GEMM: M=8512, N=2304, K=768 (bf16 in -> bf16 Q/K/VT)
    gemm_nt<0, false, false><<<dim3(36, 133, 1), 256, 0, stream>>>(
        xb, CDIM, 0LL, wb, CDIM, 0LL, CDIM, 3 * CDIM,
        Q, Kt, VT, nullptr, nullptr, 0);

    // 2. text attention (rows 0..39 of AO per batch; overwrites xb region = fine, xb dead)
    text_attn<<<96, 256, 0, stream>>>(Q, Kt, VT, AO);

    // 3. flash image attention: 8 Q-tiles x 96 (b,h)
    flash_img<<<dim3(8, 96), 256, 0, stream>>>(Q, Kt, VT, AO);

    // 4. proj GEMM + bias: M=8512, N=768, K=768 (bf16 x bf16 -> fp32 out)
    gemm_nt<3, false, false><<<dim3(12, 133, 1), 256, 0, stream>>>(
        AO, CDIM, 0LL, pb, CDIM, 0LL, CDIM, CDIM,
        nullptr, nullptr, nullptr, out, proj_b, 0);
}

// Round 4
// 273.058 us; speedup vs baseline: 1.8171x; 1.0705x over previous
//
#include <hip/hip_runtime.h>
#include <hip/hip_bf16.h>

typedef __bf16 bf16x8 __attribute__((ext_vector_type(8)));
typedef float f32x4 __attribute__((ext_vector_type(4)));

#define NHEADS 12
#define TT 40
#define ST 1024
#define NTOK 1064
#define CDIM 768
#define HD 64

union U4 {
    uint4 u;
    __hip_bfloat16 h[8];
    bf16x8 v;
};

__device__ __forceinline__ void load_lds16(const __hip_bfloat16* g, __hip_bfloat16* s)
{
    __builtin_amdgcn_global_load_lds(
        (const __attribute__((address_space(1))) void*)g,
        (__attribute__((address_space(3))) void*)s, 16, 0, 0);
}

// Fused fp32 -> bf16 convert for x, qkv_w, proj_w (8 elems/thread).
// Block ranges: [0,3192) x ; [3192,4056) qkv_w ; [4056,4344) proj_w
__global__ __launch_bounds__(256) void f2b3(
    const float* __restrict__ x,  __hip_bfloat16* __restrict__ xo,
    const float* __restrict__ w,  __hip_bfloat16* __restrict__ wo,
    const float* __restrict__ p,  __hip_bfloat16* __restrict__ po)
{
    const float* in; __hip_bfloat16* out; int i;
    if (blockIdx.x < 3192)      { in = x; out = xo; i = blockIdx.x * 256 + threadIdx.x; if (i >= 817152) return; }
    else if (blockIdx.x < 4056) { in = w; out = wo; i = (blockIdx.x - 3192) * 256 + threadIdx.x; if (i >= 221184) return; }
    else                        { in = p; out = po; i = (blockIdx.x - 4056) * 256 + threadIdx.x; if (i >= 73728) return; }
    float4 a = ((const float4*)in)[2 * i];
    float4 b = ((const float4*)in)[2 * i + 1];
    U4 r;
    r.h[0] = __float2bfloat16(a.x); r.h[1] = __float2bfloat16(a.y);
    r.h[2] = __float2bfloat16(a.z); r.h[3] = __float2bfloat16(a.w);
    r.h[4] = __float2bfloat16(b.x); r.h[5] = __float2bfloat16(b.y);
    r.h[6] = __float2bfloat16(b.z); r.h[7] = __float2bfloat16(b.w);
    ((uint4*)out)[i] = r.u;
}

// ---------------------------------------------------------------------------
// 128x128x32 NT GEMM (m97 structure): 256 thr = 4 waves, each wave 64x64 via
// 4x4 grid of 16x16x32 bf16 MFMA. Staging: global_load_lds width=16 with
// k-segment XOR swizzle (chunk(r,cs) holds global seg (cs-(r>>1))&3) so frag
// ds_read_b128 is 2-way-conflict max (free).
// MODE 0: QKV scatter -> Q,K,VT   MODE 3: proj + bias -> fp32 out
// ---------------------------------------------------------------------------
template <int MODE>
__global__ __launch_bounds__(256) void gemm128(
    const __hip_bfloat16* __restrict__ A, int lda, int M,
    const __hip_bfloat16* __restrict__ B, int ldb,
    int K,
    __hip_bfloat16* __restrict__ out0,
    __hip_bfloat16* __restrict__ out1,
    __hip_bfloat16* __restrict__ out2,
    float* __restrict__ outf,
    const float* __restrict__ biasf)
{
    __shared__ __hip_bfloat16 lds[2 * 128 * 32];   // 16 KB
    __hip_bfloat16* ldsA = lds;
    __hip_bfloat16* ldsB = lds + 128 * 32;

    const int tid = threadIdx.x;
    const int m0 = blockIdx.y * 128;
    const int n0 = blockIdx.x * 128;
    const int w = tid >> 6, l = tid & 63, l15 = l & 15, lq = l >> 4;
    const int wm = w >> 1, wn = w & 1;

    // staging source pointers (chunk c = tid + rd*256 -> row c>>2, slot c&3)
    const __hip_bfloat16* srcA[2];
    const __hip_bfloat16* srcB[2];
#pragma unroll
    for (int rd = 0; rd < 2; ++rd) {
        const int c = tid + rd * 256;
        const int r = c >> 2, cs = c & 3;
        const int gs = (cs - (r >> 1)) & 3;          // global k-segment stored here
        int ra = m0 + r; if (ra > M - 1) ra = M - 1; // clamp (dup rows, outputs guarded)
        srcA[rd] = A + (long long)ra * lda + gs * 8;
        srcB[rd] = B + (long long)(n0 + r) * ldb + gs * 8;
    }

    // loop-invariant LDS frag offsets (elements)
    int offA[4], offB[4];
#pragma unroll
    for (int t = 0; t < 4; ++t) {
        { const int r = wm * 64 + t * 16 + l15;
          offA[t] = r * 32 + ((lq + (r >> 1)) & 3) * 8; }
        { const int r = wn * 64 + t * 16 + l15;
          offB[t] = r * 32 + ((lq + (r >> 1)) & 3) * 8; }
    }

    f32x4 acc[4][4] = {};

    const int ksteps = K / 32;
    for (int ks = 0; ks < ksteps; ++ks) {
        __syncthreads();                              // WAR: prev frag reads done
#pragma unroll
        for (int rd = 0; rd < 2; ++rd) {
            const int c8 = (tid + rd * 256) * 8;
            load_lds16(srcA[rd] + ks * 32, ldsA + c8);
            load_lds16(srcB[rd] + ks * 32, ldsB + c8);
        }
        __syncthreads();                              // RAW: vmcnt(0) drain + barrier

        bf16x8 af[4], bfr[4];
#pragma unroll
        for (int t = 0; t < 4; ++t) af[t] = *(const bf16x8*)(ldsA + offA[t]);
#pragma unroll
        for (int t = 0; t < 4; ++t) bfr[t] = *(const bf16x8*)(ldsB + offB[t]);
#pragma unroll
        for (int tr = 0; tr < 4; ++tr)
#pragma unroll
            for (int tc = 0; tc < 4; ++tc)
                acc[tr][tc] = __builtin_amdgcn_mfma_f32_16x16x32_bf16(af[tr], bfr[tc], acc[tr][tc], 0, 0, 0);
    }

#pragma unroll
    for (int tr = 0; tr < 4; ++tr) {
#pragma unroll
        for (int tc = 0; tc < 4; ++tc) {
            const int col = n0 + wn * 64 + tc * 16 + l15;
#pragma unroll
            for (int i = 0; i < 4; ++i) {
                const int row = m0 + wm * 64 + tr * 16 + lq * 4 + i;
                if (row >= M) continue;
                const float v = acc[tr][tc][i];
                if (MODE == 0) {
                    const int b = row / NTOK;
                    const int n = row - b * NTOK;
                    const int tq = col / CDIM;
                    const int rem = col - tq * CDIM;
                    const int h = rem >> 6;
                    const int e = rem & 63;
                    const long long gh = (long long)b * NHEADS + h;
                    const __hip_bfloat16 hv = __float2bfloat16(v);
                    if (tq == 0)      out0[(gh * NTOK + n) * HD + e] = hv;   // Q [b,h,n,e]
                    else if (tq == 1) out1[(gh * NTOK + n) * HD + e] = hv;   // K [b,h,n,e]
                    else              out2[(gh * HD + e) * NTOK + n] = hv;   // VT [b,h,e,n]
                } else {
                    outf[(long long)row * CDIM + col] = v + biasf[col];
                }
            }
        }
    }
}

// ---------------------------------------------------------------------------
// Flash image attention (unchanged from round 3).
// ---------------------------------------------------------------------------
__global__ __launch_bounds__(256) void flash_img(
    const __hip_bfloat16* __restrict__ Q,   // [96][1064][64]
    const __hip_bfloat16* __restrict__ Kt,  // [96][1064][64]
    const __hip_bfloat16* __restrict__ VT,  // [96][64][1064]
    __hip_bfloat16* __restrict__ AO)        // [8][1064][768]
{
    __shared__ __hip_bfloat16 smem[2 * 64 * 72];
    __hip_bfloat16* kbuf = smem;
    __hip_bfloat16* vbuf = smem + 64 * 72;

    const int gh = blockIdx.y;
    const int qt = blockIdx.x;
    const int tid = threadIdx.x;
    const int w = tid >> 6, l = tid & 63, l15 = l & 15, lq = l >> 4;

    const __hip_bfloat16* Qg = Q + ((long long)gh * NTOK + TT + qt * 128) * HD;
    const __hip_bfloat16* Kg = Kt + (long long)gh * NTOK * HD;
    const __hip_bfloat16* Vg = VT + (long long)gh * HD * NTOK;

    bf16x8 qf[2][2];
#pragma unroll
    for (int s = 0; s < 2; ++s)
#pragma unroll
        for (int kk = 0; kk < 2; ++kk)
            qf[s][kk] = *(const bf16x8*)(Qg + (w * 32 + s * 16 + l15) * HD + kk * 32 + lq * 8);

    f32x4 ot[4][2] = {};
    float mrow[2] = {-3e38f, -3e38f};
    float lrow[2] = {0.0f, 0.0f};

    for (int kt = 0; kt < 17; ++kt) {
        const int n0 = kt * 64;
        if (kt) __syncthreads();
        {
            const int r = tid >> 2, c16 = (tid & 3) * 16;
            if (kt < 16) {
                *(uint4*)(kbuf + r * 72 + c16)     = *(const uint4*)(Kg + (long long)(n0 + r) * HD + c16);
                *(uint4*)(kbuf + r * 72 + c16 + 8) = *(const uint4*)(Kg + (long long)(n0 + r) * HD + c16 + 8);
                *(uint4*)(vbuf + r * 72 + c16)     = *(const uint4*)(Vg + (long long)r * NTOK + n0 + c16);
                *(uint4*)(vbuf + r * 72 + c16 + 8) = *(const uint4*)(Vg + (long long)r * NTOK + n0 + c16 + 8);
            } else {
                const uint4 z = make_uint4(0u, 0u, 0u, 0u);
                if (n0 + r < NTOK) {
                    *(uint4*)(kbuf + r * 72 + c16)     = *(const uint4*)(Kg + (long long)(n0 + r) * HD + c16);
                    *(uint4*)(kbuf + r * 72 + c16 + 8) = *(const uint4*)(Kg + (long long)(n0 + r) * HD + c16 + 8);
                } else {
                    *(uint4*)(kbuf + r * 72 + c16) = z;
                    *(uint4*)(kbuf + r * 72 + c16 + 8) = z;
                }
                for (int j = 0; j < 16; ++j) {
                    const int cc = c16 + j;
                    vbuf[r * 72 + cc] = (n0 + cc < NTOK) ? Vg[(long long)r * NTOK + n0 + cc]
                                                         : __float2bfloat16(0.0f);
                }
            }
        }
        __syncthreads();

        f32x4 st[4][2] = {};
#pragma unroll
        for (int kk = 0; kk < 2; ++kk) {
            bf16x8 kf[4];
#pragma unroll
            for (int t = 0; t < 4; ++t)
                kf[t] = *(const bf16x8*)(kbuf + (t * 16 + l15) * 72 + kk * 32 + lq * 8);
#pragma unroll
            for (int t = 0; t < 4; ++t)
#pragma unroll
                for (int s = 0; s < 2; ++s)
                    st[t][s] = __builtin_amdgcn_mfma_f32_16x16x32_bf16(kf[t], qf[s][kk], st[t][s], 0, 0, 0);
        }

        float alpha[2];
#pragma unroll
        for (int s = 0; s < 2; ++s) {
            float mx = -3e38f;
#pragma unroll
            for (int t = 0; t < 4; ++t)
#pragma unroll
                for (int i = 0; i < 4; ++i) {
                    const int n = n0 + t * 16 + lq * 4 + i;
                    const float sv = (n < NTOK) ? st[t][s][i] * 0.125f : -3e38f;
                    st[t][s][i] = sv;
                    mx = fmaxf(mx, sv);
                }
            mx = fmaxf(mx, __shfl_xor(mx, 16));
            mx = fmaxf(mx, __shfl_xor(mx, 32));
            const float mnew = fmaxf(mrow[s], mx);
            alpha[s] = __expf(mrow[s] - mnew);
            float rs = 0.0f;
#pragma unroll
            for (int t = 0; t < 4; ++t)
#pragma unroll
                for (int i = 0; i < 4; ++i) {
                    const float e = __expf(st[t][s][i] - mnew);
                    st[t][s][i] = e;
                    rs += e;
                }
            rs += __shfl_xor(rs, 16);
            rs += __shfl_xor(rs, 32);
            lrow[s] = lrow[s] * alpha[s] + rs;
            mrow[s] = mnew;
        }

#pragma unroll
        for (int te = 0; te < 4; ++te)
#pragma unroll
            for (int s = 0; s < 2; ++s)
#pragma unroll
                for (int i = 0; i < 4; ++i)
                    ot[te][s][i] *= alpha[s];

        unsigned pk[4][2][2];
#pragma unroll
        for (int t = 0; t < 4; ++t)
#pragma unroll
            for (int s = 0; s < 2; ++s)
#pragma unroll
                for (int h = 0; h < 2; ++h) {
                    __hip_bfloat162 b2;
                    b2.x = __float2bfloat16(st[t][s][2 * h]);
                    b2.y = __float2bfloat16(st[t][s][2 * h + 1]);
                    pk[t][s][h] = *(unsigned*)&b2;
                }

        const int L0 = ((l & 16) ? 32 : 0) + l15;
        const int L1 = L0 + 16;
        const bool hi = (l & 32) != 0;
#pragma unroll
        for (int kk = 0; kk < 2; ++kk) {
            bf16x8 vf[4];
#pragma unroll
            for (int te = 0; te < 4; ++te)
                vf[te] = *(const bf16x8*)(vbuf + (te * 16 + l15) * 72 + kk * 32 + lq * 8);
#pragma unroll
            for (int s = 0; s < 2; ++s) {
                const unsigned a0 = __shfl(pk[2 * kk][s][0], L0), b0 = __shfl(pk[2 * kk + 1][s][0], L0);
                const unsigned a1 = __shfl(pk[2 * kk][s][1], L0), b1 = __shfl(pk[2 * kk + 1][s][1], L0);
                const unsigned a2 = __shfl(pk[2 * kk][s][0], L1), b2 = __shfl(pk[2 * kk + 1][s][0], L1);
                const unsigned a3 = __shfl(pk[2 * kk][s][1], L1), b3 = __shfl(pk[2 * kk + 1][s][1], L1);
                union { unsigned u[4]; bf16x8 v; } pu;
                pu.u[0] = hi ? b0 : a0;
                pu.u[1] = hi ? b1 : a1;
                pu.u[2] = hi ? b2 : a2;
                pu.u[3] = hi ? b3 : a3;
#pragma unroll
                for (int te = 0; te < 4; ++te)
                    ot[te][s] = __builtin_amdgcn_mfma_f32_16x16x32_bf16(vf[te], pu.v, ot[te][s], 0, 0, 0);
            }
        }
    }

    __syncthreads();
    __hip_bfloat16* obuf = smem;
    const float inv[2] = {1.0f / lrow[0], 1.0f / lrow[1]};
#pragma unroll
    for (int te = 0; te < 4; ++te)
#pragma unroll
        for (int s = 0; s < 2; ++s) {
            __hip_bfloat162 x0, x1;
            x0.x = __float2bfloat16(ot[te][s][0] * inv[s]);
            x0.y = __float2bfloat16(ot[te][s][1] * inv[s]);
            x1.x = __float2bfloat16(ot[te][s][2] * inv[s]);
            x1.y = __float2bfloat16(ot[te][s][3] * inv[s]);
            uint2 u;
            u.x = *(unsigned*)&x0;
            u.y = *(unsigned*)&x1;
            *(uint2*)(obuf + (w * 32 + s * 16 + l15) * 72 + te * 16 + lq * 4) = u;
        }
    __syncthreads();
    {
        const int b = gh / NHEADS, h = gh - b * NHEADS;
        const int r = tid >> 1, c0 = (tid & 1) * 32;
        const int token = TT + qt * 128 + r;
        __hip_bfloat16* dst = AO + ((long long)b * NTOK + token) * CDIM + h * HD + c0;
#pragma unroll
        for (int i = 0; i < 4; ++i)
            *(uint4*)(dst + i * 8) = *(const uint4*)(obuf + r * 72 + c0 + i * 8);
    }
}

// Text attention (unchanged).
__global__ __launch_bounds__(256) void text_attn(
    const __hip_bfloat16* __restrict__ Q,
    const __hip_bfloat16* __restrict__ Kt,
    const __hip_bfloat16* __restrict__ VT,
    __hip_bfloat16* __restrict__ AO)
{
    const int gh = blockIdx.x;
    const int b = gh / NHEADS;
    const int h = gh - b * NHEADS;
    __shared__ float smem[3 * 40 * 65];
    float* Qs = smem;
    float* Ks = smem + 40 * 65;
    float* Vs = smem + 2 * 40 * 65;
    const __hip_bfloat16* Qg = Q + (long long)gh * NTOK * HD;
    const __hip_bfloat16* Kg = Kt + (long long)gh * NTOK * HD;
    const __hip_bfloat16* Vg = VT + (long long)gh * HD * NTOK;
    for (int idx = threadIdx.x; idx < 40 * 64; idx += 256) {
        const int n = idx >> 6;
        const int e = idx & 63;
        Qs[n * 65 + e] = __bfloat162float(Qg[n * HD + e]);
        Ks[n * 65 + e] = __bfloat162float(Kg[n * HD + e]);
        Vs[n * 65 + e] = __bfloat162float(Vg[(long long)e * NTOK + n]);
    }
    __syncthreads();
    const int w = threadIdx.x >> 6;
    const int lane = threadIdx.x & 63;
    for (int i = w; i < TT; i += 4) {
        float s = -1e30f;
        if (lane < TT) {
            float a = 0.0f;
            for (int e = 0; e < 64; ++e) a += Qs[i * 65 + e] * Ks[lane * 65 + e];
            s = a * 0.125f;
        }
        float m = s;
        for (int off = 32; off > 0; off >>= 1) m = fmaxf(m, __shfl_xor(m, off));
        float pr = (lane < TT) ? __expf(s - m) : 0.0f;
        float ssum = pr;
        for (int off = 32; off > 0; off >>= 1) ssum += __shfl_xor(ssum, off);
        pr /= ssum;
        float o = 0.0f;
        for (int j = 0; j < TT; ++j) o += __shfl(pr, j) * Vs[j * 65 + lane];
        AO[((long long)b * NTOK + i) * CDIM + h * HD + lane] = __float2bfloat16(o);
    }
}

extern "C" void kernel_launch(void* const* d_in, const int* in_sizes, int n_in,
                              void* d_out, int out_size, void* d_ws, size_t ws_size,
                              hipStream_t stream)
{
    const float* x      = (const float*)d_in[0];
    const float* qkv_w  = (const float*)d_in[1];
    const float* proj_w = (const float*)d_in[2];
    const float* proj_b = (const float*)d_in[3];
    float* out = (float*)d_out;

    const long long QKV_ELEMS = (long long)8 * NHEADS * NTOK * HD;  // 6,537,216
    __hip_bfloat16* Q  = (__hip_bfloat16*)d_ws;
    __hip_bfloat16* Kt = Q + QKV_ELEMS;
    __hip_bfloat16* VT = Kt + QKV_ELEMS;
    __hip_bfloat16* AO = VT + QKV_ELEMS;        // [8][1064][768]; ALIASES xb (dead after QKV)
    __hip_bfloat16* xb = AO;
    __hip_bfloat16* wb = AO + QKV_ELEMS;        // qkv_w bf16 [2304][768]
    __hip_bfloat16* pb = wb + (long long)3 * CDIM * CDIM;  // proj_w bf16 [768][768]

    // 0. fused fp32 -> bf16 converts
    f2b3<<<4344, 256, 0, stream>>>(x, xb, qkv_w, wb, proj_w, pb);

    // 1. QKV GEMM: M=8512, N=2304, K=768 -> scatter Q/K/VT
    gemm128<0><<<dim3(18, 67), 256, 0, stream>>>(
        xb, CDIM, 8 * NTOK, wb, CDIM, CDIM,
        Q, Kt, VT, nullptr, nullptr);

    // 2. text attention
    text_attn<<<96, 256, 0, stream>>>(Q, Kt, VT, AO);

    // 3. flash image attention
    flash_img<<<dim3(8, 96), 256, 0, stream>>>(Q, Kt, VT, AO);

    // 4. proj GEMM + bias -> fp32 out
    gemm128<3><<<dim3(6, 67), 256, 0, stream>>>(
        AO, CDIM, 8 * NTOK, pb, CDIM, CDIM,
        nullptr, nullptr, nullptr, out, proj_b);
}

// Round 5
// 258.734 us; speedup vs baseline: 1.9177x; 1.0554x over previous
//
#include <hip/hip_runtime.h>
#include <hip/hip_bf16.h>

typedef __bf16 bf16x8 __attribute__((ext_vector_type(8)));
typedef float f32x4 __attribute__((ext_vector_type(4)));

#define NHEADS 12
#define TT 40
#define ST 1024
#define NTOK 1064
#define CDIM 768
#define HD 64

union U4 {
    uint4 u;
    __hip_bfloat16 h[8];
    bf16x8 v;
};

__device__ __forceinline__ void load_lds16(const __hip_bfloat16* g, __hip_bfloat16* s)
{
    __builtin_amdgcn_global_load_lds(
        (const __attribute__((address_space(1))) void*)g,
        (__attribute__((address_space(3))) void*)s, 16, 0, 0);
}

// Fused fp32 -> bf16 convert for x, qkv_w, proj_w (8 elems/thread).
__global__ __launch_bounds__(256) void f2b3(
    const float* __restrict__ x,  __hip_bfloat16* __restrict__ xo,
    const float* __restrict__ w,  __hip_bfloat16* __restrict__ wo,
    const float* __restrict__ p,  __hip_bfloat16* __restrict__ po)
{
    const float* in; __hip_bfloat16* out; int i;
    if (blockIdx.x < 3192)      { in = x; out = xo; i = blockIdx.x * 256 + threadIdx.x; if (i >= 817152) return; }
    else if (blockIdx.x < 4056) { in = w; out = wo; i = (blockIdx.x - 3192) * 256 + threadIdx.x; if (i >= 221184) return; }
    else                        { in = p; out = po; i = (blockIdx.x - 4056) * 256 + threadIdx.x; if (i >= 73728) return; }
    float4 a = ((const float4*)in)[2 * i];
    float4 b = ((const float4*)in)[2 * i + 1];
    U4 r;
    r.h[0] = __float2bfloat16(a.x); r.h[1] = __float2bfloat16(a.y);
    r.h[2] = __float2bfloat16(a.z); r.h[3] = __float2bfloat16(a.w);
    r.h[4] = __float2bfloat16(b.x); r.h[5] = __float2bfloat16(b.y);
    r.h[6] = __float2bfloat16(b.z); r.h[7] = __float2bfloat16(b.w);
    ((uint4*)out)[i] = r.u;
}

// ---------------------------------------------------------------------------
// 128x128x32 NT GEMM. MODE 0: QKV scatter (VT cols via LDS-transposed
// coalesced epilogue). MODE 3: proj + bias -> fp32 out.
// ---------------------------------------------------------------------------
template <int MODE>
__global__ __launch_bounds__(256) void gemm128(
    const __hip_bfloat16* __restrict__ A, int lda, int M,
    const __hip_bfloat16* __restrict__ B, int ldb,
    int K,
    __hip_bfloat16* __restrict__ out0,
    __hip_bfloat16* __restrict__ out1,
    __hip_bfloat16* __restrict__ out2,
    float* __restrict__ outf,
    const float* __restrict__ biasf)
{
    __shared__ __hip_bfloat16 lds[8704];           // staging 8192 (16KB) | VT-transpose 64x136
    __hip_bfloat16* ldsA = lds;
    __hip_bfloat16* ldsB = lds + 128 * 32;

    const int tid = threadIdx.x;
    const int m0 = blockIdx.y * 128;
    const int n0 = blockIdx.x * 128;
    const int w = tid >> 6, l = tid & 63, l15 = l & 15, lq = l >> 4;
    const int wm = w >> 1, wn = w & 1;

    const __hip_bfloat16* srcA[2];
    const __hip_bfloat16* srcB[2];
#pragma unroll
    for (int rd = 0; rd < 2; ++rd) {
        const int c = tid + rd * 256;
        const int r = c >> 2, cs = c & 3;
        const int gs = (cs - (r >> 1)) & 3;
        int ra = m0 + r; if (ra > M - 1) ra = M - 1;
        srcA[rd] = A + (long long)ra * lda + gs * 8;
        srcB[rd] = B + (long long)(n0 + r) * ldb + gs * 8;
    }

    int offA[4], offB[4];
#pragma unroll
    for (int t = 0; t < 4; ++t) {
        { const int r = wm * 64 + t * 16 + l15;
          offA[t] = r * 32 + ((lq + (r >> 1)) & 3) * 8; }
        { const int r = wn * 64 + t * 16 + l15;
          offB[t] = r * 32 + ((lq + (r >> 1)) & 3) * 8; }
    }

    f32x4 acc[4][4] = {};

    const int ksteps = K / 32;
    for (int ks = 0; ks < ksteps; ++ks) {
        __syncthreads();
#pragma unroll
        for (int rd = 0; rd < 2; ++rd) {
            const int c8 = (tid + rd * 256) * 8;
            load_lds16(srcA[rd] + ks * 32, ldsA + c8);
            load_lds16(srcB[rd] + ks * 32, ldsB + c8);
        }
        __syncthreads();

        bf16x8 af[4], bfr[4];
#pragma unroll
        for (int t = 0; t < 4; ++t) af[t] = *(const bf16x8*)(ldsA + offA[t]);
#pragma unroll
        for (int t = 0; t < 4; ++t) bfr[t] = *(const bf16x8*)(ldsB + offB[t]);
#pragma unroll
        for (int tr = 0; tr < 4; ++tr)
#pragma unroll
            for (int tc = 0; tc < 4; ++tc)
                acc[tr][tc] = __builtin_amdgcn_mfma_f32_16x16x32_bf16(af[tr], bfr[tc], acc[tr][tc], 0, 0, 0);
    }

    if (MODE == 0 && n0 >= 1536) {
        // ---- VT blocks: LDS transpose -> coalesced stores along n ----
        __hip_bfloat16* ldsT = lds;                  // [64 cols][136 rows]
#pragma unroll
        for (int hf = 0; hf < 2; ++hf) {
            __syncthreads();
            if (wn == hf) {
#pragma unroll
                for (int tr = 0; tr < 4; ++tr)
#pragma unroll
                    for (int tc = 0; tc < 4; ++tc) {
                        const int cl = tc * 16 + l15;
                        const int r = wm * 64 + tr * 16 + lq * 4;
                        U4 pk4;
                        pk4.h[0] = __float2bfloat16(acc[tr][tc][0]);
                        pk4.h[1] = __float2bfloat16(acc[tr][tc][1]);
                        pk4.h[2] = __float2bfloat16(acc[tr][tc][2]);
                        pk4.h[3] = __float2bfloat16(acc[tr][tc][3]);
                        *(uint2*)(ldsT + cl * 136 + r) = make_uint2(pk4.u.x, pk4.u.y);
                    }
            }
            __syncthreads();
            const int e = tid >> 2, rseg = (tid & 3) * 32;
            const int hh = (n0 + hf * 64 - 1536) >> 6;
#pragma unroll
            for (int j4 = 0; j4 < 4; ++j4) {
                const int r = rseg + j4 * 8;
                const int row = m0 + r;
                if (row >= 8 * NTOK) continue;
                const int b = row / NTOK;
                const int n = row - b * NTOK;
                __hip_bfloat16* dst = out2 + (((long long)(b * NHEADS + hh)) * HD + e) * NTOK + n;
                if (n + 8 <= NTOK) {
                    *(uint4*)dst = *(const uint4*)(ldsT + e * 136 + r);
                } else {
                    for (int j = 0; j < 8; ++j) {
                        const int row2 = row + j;
                        const int b2 = row2 / NTOK;
                        const int n2 = row2 - b2 * NTOK;
                        out2[(((long long)(b2 * NHEADS + hh)) * HD + e) * NTOK + n2] = ldsT[e * 136 + r + j];
                    }
                }
            }
        }
    } else {
#pragma unroll
        for (int tr = 0; tr < 4; ++tr) {
#pragma unroll
            for (int tc = 0; tc < 4; ++tc) {
                const int col = n0 + wn * 64 + tc * 16 + l15;
#pragma unroll
                for (int i = 0; i < 4; ++i) {
                    const int row = m0 + wm * 64 + tr * 16 + lq * 4 + i;
                    if (row >= M) continue;
                    const float v = acc[tr][tc][i];
                    if (MODE == 0) {
                        const int b = row / NTOK;
                        const int n = row - b * NTOK;
                        const int tq = col / CDIM;
                        const int rem = col - tq * CDIM;
                        const int h = rem >> 6;
                        const int e = rem & 63;
                        const long long gh = (long long)b * NHEADS + h;
                        const __hip_bfloat16 hv = __float2bfloat16(v);
                        if (tq == 0) out0[(gh * NTOK + n) * HD + e] = hv;   // Q
                        else         out1[(gh * NTOK + n) * HD + e] = hv;   // K
                    } else {
                        outf[(long long)row * CDIM + col] = v + biasf[col];
                    }
                }
            }
        }
    }
}

// ---------------------------------------------------------------------------
// Flash image attention. Grid (96 gh, 8 qt) -> XCD = gh%8 for L2 K/V reuse.
// K/V staging software-pipelined: prefetch tile kt+1 into VGPRs during
// compute of tile kt.
// ---------------------------------------------------------------------------
__global__ __launch_bounds__(256) void flash_img(
    const __hip_bfloat16* __restrict__ Q,   // [96][1064][64]
    const __hip_bfloat16* __restrict__ Kt,  // [96][1064][64]
    const __hip_bfloat16* __restrict__ VT,  // [96][64][1064]
    __hip_bfloat16* __restrict__ AO)        // [8][1064][768]
{
    __shared__ __hip_bfloat16 smem[2 * 64 * 72];
    __hip_bfloat16* kbuf = smem;
    __hip_bfloat16* vbuf = smem + 64 * 72;

    const int gh = blockIdx.x;
    const int qt = blockIdx.y;
    const int tid = threadIdx.x;
    const int w = tid >> 6, l = tid & 63, l15 = l & 15, lq = l >> 4;
    const int sr = tid >> 2, sc = (tid & 3) * 16;    // staging row / col

    const __hip_bfloat16* Qg = Q + ((long long)gh * NTOK + TT + qt * 128) * HD;
    const __hip_bfloat16* Kg = Kt + (long long)gh * NTOK * HD;
    const __hip_bfloat16* Vg = VT + (long long)gh * HD * NTOK;

    bf16x8 qf[2][2];
#pragma unroll
    for (int s = 0; s < 2; ++s)
#pragma unroll
        for (int kk = 0; kk < 2; ++kk)
            qf[s][kk] = *(const bf16x8*)(Qg + (w * 32 + s * 16 + l15) * HD + kk * 32 + lq * 8);

    f32x4 ot[4][2] = {};
    float mrow[2] = {-3e38f, -3e38f};
    float lrow[2] = {0.0f, 0.0f};

    U4 kr0, kr1, vr0, vr1;                            // prefetch registers
    // load tile 0
    {
        kr0.u = *(const uint4*)(Kg + (long long)sr * HD + sc);
        kr1.u = *(const uint4*)(Kg + (long long)sr * HD + sc + 8);
        vr0.u = *(const uint4*)(Vg + (long long)sr * NTOK + sc);
        vr1.u = *(const uint4*)(Vg + (long long)sr * NTOK + sc + 8);
    }

    for (int kt = 0; kt < 17; ++kt) {
        const int n0 = kt * 64;
        __syncthreads();                              // LDS consumers of kt-1 done
        *(uint4*)(kbuf + sr * 72 + sc)     = kr0.u;
        *(uint4*)(kbuf + sr * 72 + sc + 8) = kr1.u;
        *(uint4*)(vbuf + sr * 72 + sc)     = vr0.u;
        *(uint4*)(vbuf + sr * 72 + sc + 8) = vr1.u;
        __syncthreads();

        if (kt < 16) {                                // prefetch tile kt+1
            const int np = (kt + 1) * 64;
            if (kt + 1 < 16) {
                kr0.u = *(const uint4*)(Kg + (long long)(np + sr) * HD + sc);
                kr1.u = *(const uint4*)(Kg + (long long)(np + sr) * HD + sc + 8);
                vr0.u = *(const uint4*)(Vg + (long long)sr * NTOK + np + sc);
                vr1.u = *(const uint4*)(Vg + (long long)sr * NTOK + np + sc + 8);
            } else {
                const uint4 z = make_uint4(0u, 0u, 0u, 0u);
                if (np + sr < NTOK) {
                    kr0.u = *(const uint4*)(Kg + (long long)(np + sr) * HD + sc);
                    kr1.u = *(const uint4*)(Kg + (long long)(np + sr) * HD + sc + 8);
                } else { kr0.u = z; kr1.u = z; }
                for (int j = 0; j < 8; ++j) {
                    const int c0 = np + sc + j, c1 = np + sc + 8 + j;
                    vr0.h[j] = (c0 < NTOK) ? Vg[(long long)sr * NTOK + c0] : __float2bfloat16(0.0f);
                    vr1.h[j] = (c1 < NTOK) ? Vg[(long long)sr * NTOK + c1] : __float2bfloat16(0.0f);
                }
            }
        }

        f32x4 st[4][2] = {};
#pragma unroll
        for (int kk = 0; kk < 2; ++kk) {
            bf16x8 kf[4];
#pragma unroll
            for (int t = 0; t < 4; ++t)
                kf[t] = *(const bf16x8*)(kbuf + (t * 16 + l15) * 72 + kk * 32 + lq * 8);
#pragma unroll
            for (int t = 0; t < 4; ++t)
#pragma unroll
                for (int s = 0; s < 2; ++s)
                    st[t][s] = __builtin_amdgcn_mfma_f32_16x16x32_bf16(kf[t], qf[s][kk], st[t][s], 0, 0, 0);
        }

        float alpha[2];
#pragma unroll
        for (int s = 0; s < 2; ++s) {
            float mx = -3e38f;
#pragma unroll
            for (int t = 0; t < 4; ++t)
#pragma unroll
                for (int i = 0; i < 4; ++i) {
                    const int n = n0 + t * 16 + lq * 4 + i;
                    const float sv = (n < NTOK) ? st[t][s][i] * 0.125f : -3e38f;
                    st[t][s][i] = sv;
                    mx = fmaxf(mx, sv);
                }
            mx = fmaxf(mx, __shfl_xor(mx, 16));
            mx = fmaxf(mx, __shfl_xor(mx, 32));
            const float mnew = fmaxf(mrow[s], mx);
            alpha[s] = __expf(mrow[s] - mnew);
            float rs = 0.0f;
#pragma unroll
            for (int t = 0; t < 4; ++t)
#pragma unroll
                for (int i = 0; i < 4; ++i) {
                    const float e = __expf(st[t][s][i] - mnew);
                    st[t][s][i] = e;
                    rs += e;
                }
            rs += __shfl_xor(rs, 16);
            rs += __shfl_xor(rs, 32);
            lrow[s] = lrow[s] * alpha[s] + rs;
            mrow[s] = mnew;
        }

#pragma unroll
        for (int te = 0; te < 4; ++te)
#pragma unroll
            for (int s = 0; s < 2; ++s)
#pragma unroll
                for (int i = 0; i < 4; ++i)
                    ot[te][s][i] *= alpha[s];

        unsigned pk[4][2][2];
#pragma unroll
        for (int t = 0; t < 4; ++t)
#pragma unroll
            for (int s = 0; s < 2; ++s)
#pragma unroll
                for (int h = 0; h < 2; ++h) {
                    __hip_bfloat162 b2;
                    b2.x = __float2bfloat16(st[t][s][2 * h]);
                    b2.y = __float2bfloat16(st[t][s][2 * h + 1]);
                    pk[t][s][h] = *(unsigned*)&b2;
                }

        const int L0 = ((l & 16) ? 32 : 0) + l15;
        const int L1 = L0 + 16;
        const bool hi = (l & 32) != 0;
#pragma unroll
        for (int kk = 0; kk < 2; ++kk) {
            bf16x8 vf[4];
#pragma unroll
            for (int te = 0; te < 4; ++te)
                vf[te] = *(const bf16x8*)(vbuf + (te * 16 + l15) * 72 + kk * 32 + lq * 8);
#pragma unroll
            for (int s = 0; s < 2; ++s) {
                const unsigned a0 = __shfl(pk[2 * kk][s][0], L0), b0 = __shfl(pk[2 * kk + 1][s][0], L0);
                const unsigned a1 = __shfl(pk[2 * kk][s][1], L0), b1 = __shfl(pk[2 * kk + 1][s][1], L0);
                const unsigned a2 = __shfl(pk[2 * kk][s][0], L1), b2 = __shfl(pk[2 * kk + 1][s][0], L1);
                const unsigned a3 = __shfl(pk[2 * kk][s][1], L1), b3 = __shfl(pk[2 * kk + 1][s][1], L1);
                union { unsigned u[4]; bf16x8 v; } pu;
                pu.u[0] = hi ? b0 : a0;
                pu.u[1] = hi ? b1 : a1;
                pu.u[2] = hi ? b2 : a2;
                pu.u[3] = hi ? b3 : a3;
#pragma unroll
                for (int te = 0; te < 4; ++te)
                    ot[te][s] = __builtin_amdgcn_mfma_f32_16x16x32_bf16(vf[te], pu.v, ot[te][s], 0, 0, 0);
            }
        }
    }

    __syncthreads();
    __hip_bfloat16* obuf = smem;
    const float inv[2] = {1.0f / lrow[0], 1.0f / lrow[1]};
#pragma unroll
    for (int te = 0; te < 4; ++te)
#pragma unroll
        for (int s = 0; s < 2; ++s) {
            __hip_bfloat162 x0, x1;
            x0.x = __float2bfloat16(ot[te][s][0] * inv[s]);
            x0.y = __float2bfloat16(ot[te][s][1] * inv[s]);
            x1.x = __float2bfloat16(ot[te][s][2] * inv[s]);
            x1.y = __float2bfloat16(ot[te][s][3] * inv[s]);
            uint2 u;
            u.x = *(unsigned*)&x0;
            u.y = *(unsigned*)&x1;
            *(uint2*)(obuf + (w * 32 + s * 16 + l15) * 72 + te * 16 + lq * 4) = u;
        }
    __syncthreads();
    {
        const int b = gh / NHEADS, h = gh - b * NHEADS;
        const int r = tid >> 1, c0 = (tid & 1) * 32;
        const int token = TT + qt * 128 + r;
        __hip_bfloat16* dst = AO + ((long long)b * NTOK + token) * CDIM + h * HD + c0;
#pragma unroll
        for (int i = 0; i < 4; ++i)
            *(uint4*)(dst + i * 8) = *(const uint4*)(obuf + r * 72 + c0 + i * 8);
    }
}

// Text attention (unchanged).
__global__ __launch_bounds__(256) void text_attn(
    const __hip_bfloat16* __restrict__ Q,
    const __hip_bfloat16* __restrict__ Kt,
    const __hip_bfloat16* __restrict__ VT,
    __hip_bfloat16* __restrict__ AO)
{
    const int gh = blockIdx.x;
    const int b = gh / NHEADS;
    const int h = gh - b * NHEADS;
    __shared__ float smem[3 * 40 * 65];
    float* Qs = smem;
    float* Ks = smem + 40 * 65;
    float* Vs = smem + 2 * 40 * 65;
    const __hip_bfloat16* Qg = Q + (long long)gh * NTOK * HD;
    const __hip_bfloat16* Kg = Kt + (long long)gh * NTOK * HD;
    const __hip_bfloat16* Vg = VT + (long long)gh * HD * NTOK;
    for (int idx = threadIdx.x; idx < 40 * 64; idx += 256) {
        const int n = idx >> 6;
        const int e = idx & 63;
        Qs[n * 65 + e] = __bfloat162float(Qg[n * HD + e]);
        Ks[n * 65 + e] = __bfloat162float(Kg[n * HD + e]);
        Vs[n * 65 + e] = __bfloat162float(Vg[(long long)e * NTOK + n]);
    }
    __syncthreads();
    const int w = threadIdx.x >> 6;
    const int lane = threadIdx.x & 63;
    for (int i = w; i < TT; i += 4) {
        float s = -1e30f;
        if (lane < TT) {
            float a = 0.0f;
            for (int e = 0; e < 64; ++e) a += Qs[i * 65 + e] * Ks[lane * 65 + e];
            s = a * 0.125f;
        }
        float m = s;
        for (int off = 32; off > 0; off >>= 1) m = fmaxf(m, __shfl_xor(m, off));
        float pr = (lane < TT) ? __expf(s - m) : 0.0f;
        float ssum = pr;
        for (int off = 32; off > 0; off >>= 1) ssum += __shfl_xor(ssum, off);
        pr /= ssum;
        float o = 0.0f;
        for (int j = 0; j < TT; ++j) o += __shfl(pr, j) * Vs[j * 65 + lane];
        AO[((long long)b * NTOK + i) * CDIM + h * HD + lane] = __float2bfloat16(o);
    }
}

extern "C" void kernel_launch(void* const* d_in, const int* in_sizes, int n_in,
                              void* d_out, int out_size, void* d_ws, size_t ws_size,
                              hipStream_t stream)
{
    const float* x      = (const float*)d_in[0];
    const float* qkv_w  = (const float*)d_in[1];
    const float* proj_w = (const float*)d_in[2];
    const float* proj_b = (const float*)d_in[3];
    float* out = (float*)d_out;

    const long long QKV_ELEMS = (long long)8 * NHEADS * NTOK * HD;  // 6,537,216
    __hip_bfloat16* Q  = (__hip_bfloat16*)d_ws;
    __hip_bfloat16* Kt = Q + QKV_ELEMS;
    __hip_bfloat16* VT = Kt + QKV_ELEMS;
    __hip_bfloat16* AO = VT + QKV_ELEMS;        // [8][1064][768]; ALIASES xb (dead after QKV)
    __hip_bfloat16* xb = AO;
    __hip_bfloat16* wb = AO + QKV_ELEMS;        // qkv_w bf16 [2304][768]
    __hip_bfloat16* pb = wb + (long long)3 * CDIM * CDIM;  // proj_w bf16 [768][768]

    // 0. fused fp32 -> bf16 converts
    f2b3<<<4344, 256, 0, stream>>>(x, xb, qkv_w, wb, proj_w, pb);

    // 1. QKV GEMM: M=8512, N=2304, K=768 -> scatter Q/K/VT
    gemm128<0><<<dim3(18, 67), 256, 0, stream>>>(
        xb, CDIM, 8 * NTOK, wb, CDIM, CDIM,
        Q, Kt, VT, nullptr, nullptr);

    // 2. text attention
    text_attn<<<96, 256, 0, stream>>>(Q, Kt, VT, AO);

    // 3. flash image attention (gh fastest -> XCD-local K/V)
    flash_img<<<dim3(96, 8), 256, 0, stream>>>(Q, Kt, VT, AO);

    // 4. proj GEMM + bias -> fp32 out
    gemm128<3><<<dim3(6, 67), 256, 0, stream>>>(
        AO, CDIM, 8 * NTOK, pb, CDIM, CDIM,
        nullptr, nullptr, nullptr, out, proj_b);
}